// Round 6
// baseline (77.928 us; speedup 1.0000x reference)
//
#include <hip/hip_runtime.h>
#include <math.h>

#define GNUM 16
#define CDIM 128
#define SLOT (GNUM*CDIM + 2*GNUM)   // 2080 floats per partial slot
#define NBMAX 1024
#define NRSL 8                       // row-slices for the K2 reduction

typedef float v2f __attribute__((ext_vector_type(2)));

// ---------------- Kernel 1: normalize + register-resident segment accumulate ----------------
// 256 threads = 4 waves. GRID-STRIDED pairs: wave gw processes p = gw, gw+nw, gw+2nw...
// so at any instant the 4096 waves' requests cover a contiguous ~4MB band ->
// adjacent 1KB blocks are fetched near-simultaneously by adjacent waves (DRAM row reuse),
// unlike contiguous per-wave chunks where consecutive blocks arrive ~1us apart.
// Per pair p: lane loads float4 -> lanes 0-31 = row 2p, lanes 32-63 = row 2p+1.
// Depth-6 rotating register ring keeps 6KB of loads in flight per wave.
__global__ __launch_bounds__(256, 4)
void oc_accum(const float* __restrict__ feat, const int* __restrict__ scores,
              float* __restrict__ partial, int B, int npairs)
{
    __shared__ float ws_sum[4][GNUM][CDIM];   // 32 KB, epilogue only
    __shared__ float ws_cnt[4][GNUM];
    __shared__ float ws_sq [4][GNUM];

    const int tid  = threadIdx.x;
    const int wave = tid >> 6;
    const int lane = tid & 63;
    const int hl   = lane & 31;       // lane within half-wave (channels hl*4..hl*4+3)
    const int half = lane >> 5;       // which row of the pair

    v2f acc[GNUM][2];
    #pragma unroll
    for (int gg = 0; gg < GNUM; ++gg) { acc[gg][0] = (v2f)0.f; acc[gg][1] = (v2f)0.f; }
    float cnt = 0.f, sq = 0.f;

    const int gw = blockIdx.x*4 + wave;
    const int nw = gridDim.x*4;

    // strided iteration count for this wave: pairs gw + k*nw, k in [0, nit)
    const int nit = (gw < npairs) ? ((npairs - 1 - gw) / nw + 1) : 0;

    auto process = [&](float4 x, int g) {
        float ss = x.x*x.x + x.y*x.y + x.z*x.z + x.w*x.w;
        ss += __shfl_xor(ss, 1);
        ss += __shfl_xor(ss, 2);
        ss += __shfl_xor(ss, 4);
        ss += __shfl_xor(ss, 8);
        ss += __shfl_xor(ss, 16);           // masks <32 never cross the half boundary
        const float inv = (ss > 1e-24f) ? rsqrtf(ss) : 1e12f;   // == 1/max(sqrt(ss),1e-12)
        const v2f xlo = {x.x, x.y};
        const v2f xhi = {x.z, x.w};
        #pragma unroll
        for (int gg = 0; gg < GNUM; ++gg) {
            const float w = (g == gg) ? inv : 0.0f;
            const v2f wv = {w, w};
            acc[gg][0] = xlo * wv + acc[gg][0];   // v_pk_fma_f32
            acc[gg][1] = xhi * wv + acc[gg][1];
        }
        if (g == hl) { cnt += 1.0f; sq = fmaf(ss, inv*inv, sq); }
    };

    const float4* src = reinterpret_cast<const float4*>(feat);

    if (nit > 0) {
        const int klast = nit - 1;
        // load ring slot for iteration-index k (clamped to this wave's last valid k)
        auto LD = [&](int k, float4& x, int& g) {
            const int kc = (k < klast) ? k : klast;
            const int p  = gw + kc * nw;
            x = src[(size_t)p*32 + lane];
            g = scores[2*p + half];
        };

        float4 x0,x1,x2,x3,x4,x5; int g0,g1,g2,g3,g4,g5;
        LD(0, x0,g0); LD(1, x1,g1); LD(2, x2,g2);
        LD(3, x3,g3); LD(4, x4,g4); LD(5, x5,g5);

        int k = 0;
        for (; k + 6 <= nit; k += 6) {
            process(x0,g0); LD(k+6,  x0,g0);
            process(x1,g1); LD(k+7,  x1,g1);
            process(x2,g2); LD(k+8,  x2,g2);
            process(x3,g3); LD(k+9,  x3,g3);
            process(x4,g4); LD(k+10, x4,g4);
            process(x5,g5); LD(k+11, x5,g5);
        }
        const int rem = nit - k;           // 0..5
        if (rem > 0) process(x0,g0);
        if (rem > 1) process(x1,g1);
        if (rem > 2) process(x2,g2);
        if (rem > 3) process(x3,g3);
        if (rem > 4) process(x4,g4);
    }

    // odd B: the unpaired last row, handled once by wave 0 (half-1 lanes contribute nothing)
    if ((B & 1) && gw == 0) {
        float4 xo = make_float4(0.f,0.f,0.f,0.f);
        int go = -1;
        if (half == 0) {
            xo = src[(size_t)(B-1)*32 + hl];
            go = scores[B-1];
        }
        process(xo, go);
    }

    // combine the two halves of the wave in-register
    #pragma unroll
    for (int gg = 0; gg < GNUM; ++gg) {
        acc[gg][0].x += __shfl_xor(acc[gg][0].x, 32);
        acc[gg][0].y += __shfl_xor(acc[gg][0].y, 32);
        acc[gg][1].x += __shfl_xor(acc[gg][1].x, 32);
        acc[gg][1].y += __shfl_xor(acc[gg][1].y, 32);
    }
    cnt += __shfl_xor(cnt, 32);
    sq  += __shfl_xor(sq, 32);

    // direct (non-RMW) per-wave LDS stores
    if (half == 0) {
        #pragma unroll
        for (int gg = 0; gg < GNUM; ++gg) {
            *reinterpret_cast<v2f*>(&ws_sum[wave][gg][hl*4])     = acc[gg][0];
            *reinterpret_cast<v2f*>(&ws_sum[wave][gg][hl*4 + 2]) = acc[gg][1];
        }
        if (hl < GNUM) { ws_cnt[wave][hl] = cnt; ws_sq[wave][hl] = sq; }
    }
    __syncthreads();

    // block-level reduce of the 4 wave copies, write partial slot
    float* out = partial + (size_t)blockIdx.x * SLOT;
    const float* f0 = &ws_sum[0][0][0];
    const float* f1 = &ws_sum[1][0][0];
    const float* f2 = &ws_sum[2][0][0];
    const float* f3 = &ws_sum[3][0][0];
    for (int e = tid; e < GNUM*CDIM; e += 256)
        out[e] = f0[e] + f1[e] + f2[e] + f3[e];
    if (tid < GNUM) {
        out[GNUM*CDIM + tid]        = ws_cnt[0][tid] + ws_cnt[1][tid] + ws_cnt[2][tid] + ws_cnt[3][tid];
        out[GNUM*CDIM + GNUM + tid] = ws_sq [0][tid] + ws_sq [1][tid] + ws_sq [2][tid] + ws_sq [3][tid];
    }
}

// ---------------- Kernel 2: parallel column reduction of partial slots ----------------
// grid (ceil(SLOT/64), NRSL): blockIdx.y picks a row-slice; output NRSL partial vectors.
__global__ __launch_bounds__(256)
void oc_reduce(const float* __restrict__ partial, float* __restrict__ fin8, int nb)
{
    __shared__ float sdata[256];
    const int e     = blockIdx.x*64 + (threadIdx.x & 63);
    const int blane = threadIdx.x >> 6;
    float acc = 0.f;
    if (e < SLOT)
        for (int b = blockIdx.y + blane*NRSL; b < nb; b += 4*NRSL)
            acc += partial[(size_t)b*SLOT + e];
    sdata[threadIdx.x] = acc;
    __syncthreads();
    if (threadIdx.x < 64 && e < SLOT)
        fin8[(size_t)blockIdx.y*SLOT + e] =
            sdata[threadIdx.x] + sdata[threadIdx.x + 64] +
            sdata[threadIdx.x + 128] + sdata[threadIdx.x + 192];
}

// ---------------- Kernel 3: sum slices + remap/compact + loss ----------------
__global__ __launch_bounds__(256)
void oc_loss(const float* __restrict__ fin8, float* __restrict__ out)
{
    __shared__ float FIN[SLOT];
    __shared__ float M[GNUM][CDIM];
    __shared__ float MS[GNUM];
    __shared__ float Cs[GNUM];
    __shared__ int   srcmap[GNUM];
    __shared__ int   Ush;
    __shared__ float red[4];

    const int tid = threadIdx.x;

    for (int e = tid; e < SLOT; e += 256) {
        float a = 0.f;
        #pragma unroll
        for (int r = 0; r < NRSL; ++r) a += fin8[(size_t)r*SLOT + e];
        FIN[e] = a;
    }
    __syncthreads();

    if (tid < GNUM) Cs[tid] = FIN[GNUM*CDIM + tid];
    __syncthreads();

    if (tid == 0) {
        int u = 0;
        for (int g = 0; g < GNUM; ++g)
            if (Cs[g] > 0.f) srcmap[u++] = g;
        Ush = u;
        for (int k = u; k < GNUM; ++k) srcmap[k] = -1;
    }
    __syncthreads();
    const int U = Ush;

    for (int e = tid; e < GNUM*CDIM; e += 256) {
        const int u = e >> 7, c = e & 127;
        const int g = srcmap[u];
        M[u][c] = (g >= 0) ? FIN[g*CDIM + c] / fmaxf(Cs[g], 1.f) : 0.f;
    }
    if (tid < GNUM) {
        const int g = srcmap[tid];
        MS[tid] = (g >= 0) ? FIN[GNUM*CDIM + GNUM + g] / fmaxf(Cs[g], 1.f) : 0.f;
    }
    __syncthreads();

    float acc = 0.f;
    for (int e = tid; e < (GNUM-2)*CDIM; e += 256) {
        const int i = e >> 7, c = e & 127;
        if (i + 2 < U) {
            const float m1 = M[i][c], m2 = M[i+1][c], m3 = M[i+2][c];
            acc += m2*(m1 + m3) - m1*m3;
        }
    }
    acc += __shfl_xor(acc, 1);
    acc += __shfl_xor(acc, 2);
    acc += __shfl_xor(acc, 4);
    acc += __shfl_xor(acc, 8);
    acc += __shfl_xor(acc, 16);
    acc += __shfl_xor(acc, 32);
    if ((tid & 63) == 0) red[tid >> 6] = acc;
    __syncthreads();

    if (tid == 0) {
        float tot = red[0] + red[1] + red[2] + red[3];
        for (int i = 0; i < GNUM-2; ++i)
            if (i + 2 < U) tot -= MS[i+1];
        out[0] = tot / (float)(U - 2);
    }
}

extern "C" void kernel_launch(void* const* d_in, const int* in_sizes, int n_in,
                              void* d_out, int out_size, void* d_ws, size_t ws_size,
                              hipStream_t stream) {
    const float* feat   = (const float*)d_in[0];
    const int*   scores = (const int*)d_in[1];
    float*       out    = (float*)d_out;

    const int B      = in_sizes[1];          // number of rows
    const int npairs = B / 2;                // full pairs (odd row handled in-kernel)

    // ws layout: [nb * SLOT] partial slots, then [NRSL * SLOT] slice vectors.
    long long cap = (long long)(ws_size / (SLOT * sizeof(float))) - NRSL;
    int nb = (int)(cap < 1 ? 1 : (cap > NBMAX ? NBMAX : cap));

    float* partial = (float*)d_ws;
    float* fin8    = partial + (size_t)nb * SLOT;

    hipLaunchKernelGGL(oc_accum,  dim3(nb), dim3(256), 0, stream, feat, scores, partial, B, npairs);
    hipLaunchKernelGGL(oc_reduce, dim3((SLOT + 63) / 64, NRSL), dim3(256), 0, stream, partial, fin8, nb);
    hipLaunchKernelGGL(oc_loss,   dim3(1), dim3(256), 0, stream, fin8, out);
}